// Round 19
// baseline (169.036 us; speedup 1.0000x reference)
//
#include <hip/hip_runtime.h>

// RFCN PSROI — 3 launches; proj restructured for DENSE per-CU read streams:
//   out[b,n,g] = B'[g] + (1/denom) * sum_{bin} Z[b,g,h,w]
//   Z = einsum('bchw,gc->bghw', features, W'),  W'[g,c] = sum_k w[g*9+k, c]
// K0 prep: fold weights -> Wred/Bred (blocks 0..100) + zero Z (blocks 101..300).
// K1 proj: 256 blocks (1/CU); block owns 16 CONTIGUOUS channels (2 runs of 8)
//     x a 2048-px half -> reads 128 KB as dense 8 KB runs (m13-style streams,
//     vs r14's 256B slivers at 16KB stride). Z reduced across blocks via
//     native fp32 atomics (13.1M adds, L2-served; fp-order noise << 0.23 thr).
// K2 ig: per (b,g): Z tile + 2D prefix scan + proposal gather (r14 body).

#define HW 4096      // 64*64
#define NG 25        // 21 cls + 4 reg groups
#define CIN 1024
#define B 2
#define NPROP 1000

// ---------------- Kernel 0: weight fold + Z zeroing ------------------------
// grid = 301 x 256: blocks 0..100 fold (25625 entries), 101..300 zero Z
// (51200 float4 = 204800 floats exactly).
__global__ void rfcn_prep(const float* __restrict__ w_cls,
                          const float* __restrict__ b_cls,
                          const float* __restrict__ w_reg,
                          const float* __restrict__ b_reg,
                          float* __restrict__ Wred,   // [25][1024]
                          float* __restrict__ Bred,   // [25]
                          float* __restrict__ Z) {    // [2][25][4096]
    const int bid = blockIdx.x, t = threadIdx.x;
    if (bid < 101) {
        const int i = bid * 256 + t;
        if (i < NG * CIN) {
            const int g = i >> 10, c = i & (CIN - 1);
            float s = 0.f;
            if (g < 21) {
                #pragma unroll
                for (int k = 0; k < 9; ++k) s += w_cls[(size_t)(g * 9 + k) * CIN + c];
            } else {
                const int gr = g - 21;
                #pragma unroll
                for (int k = 0; k < 9; ++k) s += w_reg[(size_t)(gr * 9 + k) * CIN + c];
            }
            Wred[i] = s;
        } else if (i < NG * CIN + NG) {
            const int g = i - NG * CIN;
            float s = 0.f;
            if (g < 21) {
                #pragma unroll
                for (int k = 0; k < 9; ++k) s += b_cls[g * 9 + k];
            } else {
                #pragma unroll
                for (int k = 0; k < 9; ++k) s += b_reg[(g - 21) * 9 + k];
            }
            Bred[g] = s;
        }
    } else {
        const int i = (bid - 101) * 256 + t;     // 0..51199
        ((float4*)Z)[i] = make_float4(0.f, 0.f, 0.f, 0.f);
    }
}

// ---------------- Kernel 1: projection, channel-major dense reads ----------
// grid = (64 octet-pairs, 2 px-halves, B) = 256 blocks (1/CU), 1024 thr.
// Block reads channels {8*op..+8} and {8*(op+64)..+8} over its 2048-px half:
// 16 rows x 8 KB dense runs = 128 KB. Thread owns one float2 px-slot for all
// 16 channels; weights via wave-uniform s_load; 50 atomics/thread to Z.
__global__ __launch_bounds__(1024)
void rfcn_proj(const float* __restrict__ feats,
               const float* __restrict__ Wred,
               float* __restrict__ Z) {
    const int t = threadIdx.x;
    const int op = blockIdx.x;               // 0..63
    const int half = blockIdx.y;             // 0..1
    const int b = blockIdx.z;
    const int px = half * 2048 + 2 * t;      // float2 pixel slot

    float2 acc[NG];
    #pragma unroll
    for (int g = 0; g < NG; ++g) acc[g] = make_float2(0.f, 0.f);

    #pragma unroll
    for (int run = 0; run < 2; ++run) {
        const int c0 = (op + run * 64) * 8;  // first of 8 contiguous channels
        const float2* __restrict__ f2 =
            (const float2*)(feats + ((size_t)(b * CIN + c0)) * HW + px);
        const float* __restrict__ wgt = Wred + c0;   // scalar-indexed

        #pragma unroll
        for (int cc = 0; cc < 8; cc += 4) {
            float2 fv[4];
            #pragma unroll
            for (int j = 0; j < 4; ++j) fv[j] = f2[(size_t)(cc + j) * (HW / 2)];
            #pragma unroll
            for (int j = 0; j < 4; ++j)
                #pragma unroll
                for (int g = 0; g < NG; ++g) {
                    const float w = wgt[g * CIN + cc + j];
                    acc[g].x += fv[j].x * w;
                    acc[g].y += fv[j].y * w;
                }
        }
    }

    // cross-block reduce: native fp32 atomics (64 contributions per element)
    float* zb = Z + (size_t)(b * NG) * HW + px;
    #pragma unroll
    for (int g = 0; g < NG; ++g) {
        unsafeAtomicAdd(zb + (size_t)g * HW,     acc[g].x);
        unsafeAtomicAdd(zb + (size_t)g * HW + 1, acc[g].y);
    }
}

// ---------------- Kernel 2: 2D prefix sum + proposal gather ----------------
// grid = 50 (m = b*25+g), block = 1024 (16 waves); each wave scans 4 rows
// then 4 cols (independent 6-deep shfl chains).
// LDS 64x65: pad kills row-phase conflicts; col stride 65 == 1 (mod 32).
__global__ __launch_bounds__(1024)
void rfcn_ig(const float* __restrict__ Z,
             const int* __restrict__ props,
             const float* __restrict__ Bred,
             float* __restrict__ out) {
    const int m = blockIdx.x;        // b*25 + g
    const int t = threadIdx.x;
    const int lane = t & 63;
    const int wave = t >> 6;         // 0..15
    const int b = m / NG;
    const int g = m - b * NG;        // block-uniform
    __shared__ float tile[64 * 65];

    // phase 1: load this map's 16 KB (coalesced)
    #pragma unroll
    for (int i = 0; i < 4; ++i) {
        const int idx = i * 1024 + t;
        tile[(idx >> 6) * 65 + (idx & 63)] = Z[(size_t)m * HW + idx];
    }
    __syncthreads();

    // phase 2: row scans — wave w owns rows [w*4, w*4+4), lane = column
    #pragma unroll
    for (int i = 0; i < 4; ++i) {
        const int row = wave * 4 + i;
        float v = tile[row * 65 + lane];
        #pragma unroll
        for (int d = 1; d < 64; d <<= 1) {
            float u = __shfl_up(v, (unsigned)d, 64);
            if (lane >= d) v += u;
        }
        tile[row * 65 + lane] = v;
    }
    __syncthreads();

    // phase 3: column scans — wave w owns cols [w*4, w*4+4), lane = row
    #pragma unroll
    for (int i = 0; i < 4; ++i) {
        const int col = wave * 4 + i;
        float v = tile[lane * 65 + col];
        #pragma unroll
        for (int d = 1; d < 64; d <<= 1) {
            float u = __shfl_up(v, (unsigned)d, 64);
            if (lane >= d) v += u;
        }
        tile[lane * 65 + col] = v;
    }
    __syncthreads();

    // phase 4: per-proposal 4-corner lookups straight from LDS
    const float bias = Bred[g];
    const int n = t;
    if (n < NPROP) {
        const int4 pr = ((const int4*)props)[b * NPROP + n];
        const int x1 = pr.x >> 5;            // floor(px/32), px >= 0
        const int y1 = pr.y >> 5;
        const int x2 = (pr.z + 31) >> 5;     // ceil
        const int y2 = (pr.w + 31) >> 5;
        const int wb = (x2 - x1 + 2) / 3;    // ceil((x2-x1)/3), >= 1
        const int hb = (y2 - y1 + 2) / 3;
        const int c2 = x1 + wb - 1;          // inclusive corner, <= 63
        const int r2 = y1 + hb - 1;

        float s = tile[r2 * 65 + c2];
        if (x1 > 0)           s -= tile[r2 * 65 + (x1 - 1)];
        if (y1 > 0)           s -= tile[(y1 - 1) * 65 + c2];
        if (x1 > 0 && y1 > 0) s += tile[(y1 - 1) * 65 + (x1 - 1)];
        const float v = bias + s / (float)(hb * wb);
        if (g < 21)  // block-uniform branch
            out[(size_t)(b * NPROP + n) * 21 + g] = v;
        else
            out[(size_t)(B * NPROP * 21) + (size_t)(b * NPROP + n) * 4 + (g - 21)] = v;
    }
}

extern "C" void kernel_launch(void* const* d_in, const int* in_sizes, int n_in,
                              void* d_out, int out_size, void* d_ws, size_t ws_size,
                              hipStream_t stream) {
    const float* feats = (const float*)d_in[0];  // [2,1024,64,64]
    const float* w_cls = (const float*)d_in[1];  // [189,1024]
    const float* b_cls = (const float*)d_in[2];  // [189]
    const float* w_reg = (const float*)d_in[3];  // [36,1024]
    const float* b_reg = (const float*)d_in[4];  // [36]
    const int*   props = (const int*)d_in[5];    // [2,1000,4]
    float* out = (float*)d_out;
    float* ws  = (float*)d_ws;

    // workspace layout (floats): ~0.9 MB total
    float* Wred = ws;                        // 25600
    float* Bred = ws + 25600;                // 25 (next region 128B-aligned)
    float* Zbuf = ws + 25632;                // 2*25*4096 = 204800

    rfcn_prep<<<301, 256, 0, stream>>>(w_cls, b_cls, w_reg, b_reg,
                                       Wred, Bred, Zbuf);
    rfcn_proj<<<dim3(64, 2, B), 1024, 0, stream>>>(feats, Wred, Zbuf);
    rfcn_ig<<<B * NG, 1024, 0, stream>>>(Zbuf, props, Bred, out);
}

// Round 20
// 27.720 us; speedup vs baseline: 6.0980x; 6.0980x over previous
//
#include <hip/hip_runtime.h>

// RFCN PSROI — CHAMPION RESTORE (round-14 verbatim, 27.66us best-of-session):
//   out[b,n,g] = B'[g] + (1/denom) * sum_{bin} Z[b,g,h,w]
//   Z = einsum('bchw,gc->bghw', features, W'),  W'[g,c] = sum_k w[g*9+k, c]
// (1) fold weights -> Wred/Bred, (2) project -> 25-ch partial maps
//     (4 channel chunks; 512 blocks x 512 thr = 2 blocks/CU; paired-wave
//     LDS reduce), (3) per (b,g): 4-chunk sum + 2D prefix scan + gather.
// Session-established dead ends (do not revisit): cross-block sync (r10 261us,
// r12 174us), global atomics reduce (r19 160us), in-block weight fold
// (r13/r15 +3.5us), DMA staging (r18 +3us), occupancy/vector variants (flat).

#define HW 4096      // 64*64
#define NG 25        // 21 cls + 4 reg groups
#define CIN 1024
#define B 2
#define NPROP 1000
#define NCH 4                 // channel chunks in workspace
#define CK (CIN / NCH)        // 256 channels per chunk
#define NSL 8                 // waves per proj block
#define CS (CK / NSL)         // 32 channels per wave
#define MHW (B * NG * HW)     // 204800: one partial chunk

// ---------------- Kernel 1: fold weights over the K*K=9 channel groups ----
__global__ void rfcn_wfold(const float* __restrict__ w_cls,
                           const float* __restrict__ b_cls,
                           const float* __restrict__ w_reg,
                           const float* __restrict__ b_reg,
                           float* __restrict__ Wred,   // [25][1024]
                           float* __restrict__ Bred) { // [25]
    int i = blockIdx.x * 256 + threadIdx.x;
    if (i < NG * CIN) {
        int g = i >> 10, c = i & (CIN - 1);
        float s = 0.f;
        if (g < 21) {
            #pragma unroll
            for (int k = 0; k < 9; ++k) s += w_cls[(size_t)(g * 9 + k) * CIN + c];
        } else {
            int gr = g - 21;
            #pragma unroll
            for (int k = 0; k < 9; ++k) s += w_reg[(size_t)(gr * 9 + k) * CIN + c];
        }
        Wred[i] = s;
    } else if (i < NG * CIN + NG) {
        int g = i - NG * CIN;
        float s = 0.f;
        if (g < 21) {
            #pragma unroll
            for (int k = 0; k < 9; ++k) s += b_cls[g * 9 + k];
        } else {
            #pragma unroll
            for (int k = 0; k < 9; ++k) s += b_reg[(g - 21) * 9 + k];
        }
        Bred[g] = s;
    }
}

// ---------------- Kernel 2: projection  Z_partial = W' x F ----------------
// grid = (64 px tiles, 4 chunks, B) = 512 blocks, block = 512 (8 waves)
// -> 2 independent blocks/CU (LDS 25.6 KB). Wave sl owns channels
// [chunk*256 + sl*32, +32); batches of 16 independent loads in flight.
// part layout: [chunk][b][g][4096]
__global__ __launch_bounds__(512)
void rfcn_proj(const float* __restrict__ feats,
               const float* __restrict__ Wred,
               float* __restrict__ part) {
    const int t = threadIdx.x;
    const int p = t & 63;                      // pixel within tile
    // wave id via readfirstlane -> SGPR, keeps weight loads scalar (s_load)
    const int sl = __builtin_amdgcn_readfirstlane(t >> 6);   // 0..7
    const int pix0 = blockIdx.x * 64;
    const int chunk = blockIdx.y;
    const int b = blockIdx.z;
    const int c0 = chunk * CK + sl * CS;       // wave's first channel

    const float* __restrict__ f = feats + ((size_t)b * CIN + c0) * HW + pix0 + p;
    const float* __restrict__ wgt = Wred + c0; // scalar-indexed -> s_load

    float acc[NG];
    #pragma unroll
    for (int g = 0; g < NG; ++g) acc[g] = 0.f;

    // batches of 16 independent loads in flight, then FMA
    #pragma unroll
    for (int cc = 0; cc < CS; cc += 16) {
        float fv[16];
        #pragma unroll
        for (int j = 0; j < 16; ++j) fv[j] = f[(size_t)(cc + j) * HW];
        #pragma unroll
        for (int j = 0; j < 16; ++j)
            #pragma unroll
            for (int g = 0; g < NG; ++g)
                acc[g] += fv[j] * wgt[g * CIN + cc + j];
    }

    // paired-wave LDS reduction: red[4][25][64] = 25.6 KB
    __shared__ float red[(NSL / 2) * NG * 64];
    if (sl >= 4) {
        #pragma unroll
        for (int g = 0; g < NG; ++g) red[((sl - 4) * NG + g) * 64 + p] = acc[g];
    }
    __syncthreads();
    if (sl < 4) {
        #pragma unroll
        for (int g = 0; g < NG; ++g) red[(sl * NG + g) * 64 + p] += acc[g];
    }
    __syncthreads();

    // 4->1 sum + coalesced store
    float* __restrict__ o = part + ((size_t)(chunk * B + b) * NG) * HW + pix0;
    for (int idx = t; idx < NG * 64; idx += 512) {
        const int g = idx >> 6, pp = idx & 63;
        float s = red[(0 * NG + g) * 64 + pp] + red[(1 * NG + g) * 64 + pp]
                + red[(2 * NG + g) * 64 + pp] + red[(3 * NG + g) * 64 + pp];
        o[(size_t)g * HW + pp] = s;
    }
}

// ---------------- Kernel 3: 4-chunk sum + 2D prefix sum + gather -----------
// grid = 50 (m = b*25+g), block = 1024 (16 waves) — each wave scans 4 rows
// then 4 cols (independent 6-deep shfl chains).
// LDS 64x65: pad kills row-phase conflicts; col stride 65 == 1 (mod 32).
__global__ __launch_bounds__(1024)
void rfcn_integral_gather(const float* __restrict__ part,
                          const int* __restrict__ props,
                          const float* __restrict__ Bred,
                          float* __restrict__ out) {
    const int m = blockIdx.x;        // b*25 + g
    const int t = threadIdx.x;
    const int lane = t & 63;
    const int wave = t >> 6;         // 0..15
    const int b = m / NG;
    const int g = m - b * NG;        // block-uniform
    __shared__ float tile[64 * 65];

    // phase 1: sum the 4 partial chunks (16 independent coalesced loads)
    #pragma unroll
    for (int i = 0; i < 4; ++i) {
        const int idx = i * 1024 + t;
        float v[NCH];
        #pragma unroll
        for (int ch = 0; ch < NCH; ++ch)
            v[ch] = part[(size_t)(ch * (B * NG) + m) * HW + idx];
        #pragma unroll
        for (int off = NCH / 2; off >= 1; off >>= 1)
            #pragma unroll
            for (int j = 0; j < off; ++j) v[j] += v[j + off];
        tile[(idx >> 6) * 65 + (idx & 63)] = v[0];
    }
    __syncthreads();

    // phase 2: row scans — wave w owns rows [w*4, w*4+4), lane = column
    #pragma unroll
    for (int i = 0; i < 4; ++i) {
        const int row = wave * 4 + i;
        float v = tile[row * 65 + lane];
        #pragma unroll
        for (int d = 1; d < 64; d <<= 1) {
            float u = __shfl_up(v, (unsigned)d, 64);
            if (lane >= d) v += u;
        }
        tile[row * 65 + lane] = v;
    }
    __syncthreads();

    // phase 3: column scans — wave w owns cols [w*4, w*4+4), lane = row
    #pragma unroll
    for (int i = 0; i < 4; ++i) {
        const int col = wave * 4 + i;
        float v = tile[lane * 65 + col];
        #pragma unroll
        for (int d = 1; d < 64; d <<= 1) {
            float u = __shfl_up(v, (unsigned)d, 64);
            if (lane >= d) v += u;
        }
        tile[lane * 65 + col] = v;
    }
    __syncthreads();

    // phase 4: per-proposal 4-corner lookups straight from LDS
    const float bias = Bred[g];
    const int n = t;
    if (n < NPROP) {
        const int4 pr = ((const int4*)props)[b * NPROP + n];
        const int x1 = pr.x >> 5;            // floor(px/32), px >= 0
        const int y1 = pr.y >> 5;
        const int x2 = (pr.z + 31) >> 5;     // ceil
        const int y2 = (pr.w + 31) >> 5;
        const int wb = (x2 - x1 + 2) / 3;    // ceil((x2-x1)/3), >= 1
        const int hb = (y2 - y1 + 2) / 3;
        const int c2 = x1 + wb - 1;          // inclusive corner, <= 63
        const int r2 = y1 + hb - 1;

        float s = tile[r2 * 65 + c2];
        if (x1 > 0)           s -= tile[r2 * 65 + (x1 - 1)];
        if (y1 > 0)           s -= tile[(y1 - 1) * 65 + c2];
        if (x1 > 0 && y1 > 0) s += tile[(y1 - 1) * 65 + (x1 - 1)];
        const float v = bias + s / (float)(hb * wb);
        if (g < 21)  // block-uniform branch
            out[(size_t)(b * NPROP + n) * 21 + g] = v;
        else
            out[(size_t)(B * NPROP * 21) + (size_t)(b * NPROP + n) * 4 + (g - 21)] = v;
    }
}

extern "C" void kernel_launch(void* const* d_in, const int* in_sizes, int n_in,
                              void* d_out, int out_size, void* d_ws, size_t ws_size,
                              hipStream_t stream) {
    const float* feats = (const float*)d_in[0];  // [2,1024,64,64]
    const float* w_cls = (const float*)d_in[1];  // [189,1024]
    const float* b_cls = (const float*)d_in[2];  // [189]
    const float* w_reg = (const float*)d_in[3];  // [36,1024]
    const float* b_reg = (const float*)d_in[4];  // [36]
    const int*   props = (const int*)d_in[5];    // [2,1000,4]
    float* out = (float*)d_out;
    float* ws  = (float*)d_ws;

    // workspace layout (floats): ~3.4 MB total
    float* Wred = ws;                        // 25600
    float* Bred = ws + 25600;                // 25 (next region 128B-aligned)
    float* part = ws + 25632;                // 4 * 204800

    rfcn_wfold<<<(NG * CIN + NG + 255) / 256, 256, 0, stream>>>(
        w_cls, b_cls, w_reg, b_reg, Wred, Bred);
    rfcn_proj<<<dim3(HW / 64, NCH, B), 512, 0, stream>>>(feats, Wred, part);
    rfcn_integral_gather<<<B * NG, 1024, 0, stream>>>(part, props, Bred, out);
}